// Round 1
// baseline (9282.784 us; speedup 1.0000x reference)
//
#include <hip/hip_runtime.h>

// HybridQLSTM: T=1024 steps, B=64, D=512, H=512.
// Persistent cooperative kernel; 4 batch-groups x 64 blocks.
// Each block: 8 h-cols (32 gate-cols), weight slice resident in LDS (bf16),
// c-state in LDS (fp32). Per step: MFMA z = [x,h]@W^T, fp32 gates, publish h
// bf16 via agent-scope write-through; per-block monotonic flag, group-local poll.

#define T_STEPS 1024
#define BATCH   64
#define DIM     512
#define HID     512
#define KDIM    1024   // D+H
#define NGROUPS 4
#define BPG     64     // blocks per group
#define BB      16     // batch rows per group
#define HCB     8      // h-cols per block
#define GC      32     // gate-cols per block (4 gates * HCB)

typedef __bf16 bf16_t;
typedef __bf16 bf16x4 __attribute__((ext_vector_type(4)));
typedef __bf16 bf16x8 __attribute__((ext_vector_type(8)));
typedef float  f32x4  __attribute__((ext_vector_type(4)));

// ---- ws layout ----
// [0, 1KB)            : flags[256] (u32, zeroed each launch)
// [4096, +4MB)        : Wb bf16 [64 slices][32][1024]
// [4096+4MB, +67.1MB) : hbuf bf16 [T+1][64][512]
#define WS_FLAGS_OFF 0
#define WS_WB_OFF    4096
#define WS_HBUF_OFF  (4096 + 4194304)
#define WS_REQUIRED  ((size_t)WS_HBUF_OFF + (size_t)(T_STEPS + 1) * BATCH * HID * 2)

// ---- dynamic LDS layout (bytes) ----
// Wsl  bf16 [32][1032]  @ 0       (66048)
// comb bf16 [16][1032]  @ 66048   (33024)
// zbuf f32  [2][32][17] @ 99072   (4352)
// cbuf f32  [128]       @ 103424
// htmp f32  [128]       @ 103936
// bb   f32  [32]        @ 104448
// qsh  f32  [8]         @ 104576
// qbh  f32  [8]         @ 104608
#define SMEM_BYTES 104640
#define LROW 1032  // padded row length (elements) for Wsl/comb: +16B kills bank conflicts

__global__ void prep_kernel(const float* __restrict__ Wf, const float* __restrict__ Wi,
                            const float* __restrict__ Wg, const float* __restrict__ Wo,
                            unsigned* __restrict__ flags, bf16_t* __restrict__ Wb,
                            bf16_t* __restrict__ hbuf) {
  size_t w = (size_t)blockIdx.x * 256 + threadIdx.x;
  if (w < 256) flags[w] = 0u;                       // h_{-1} "ready" for step 0
  if (w < 16384) ((unsigned*)hbuf)[w] = 0u;         // hbuf[0] = h_{-1} = 0
  if (w < 1048576) {                                // pack weights -> bf16 pairs
    int j    = (int)(w >> 14);      // slice (block-in-group)
    int rem  = (int)(w & 16383);
    int srow = rem >> 9;            // 0..31 : gate q = srow>>3, local col c = srow&7
    int k2   = rem & 511;
    int q = srow >> 3, c = srow & 7;
    int h = j * HCB + c;
    const float* W = (q == 0) ? Wf : (q == 1) ? Wi : (q == 2) ? Wg : Wo;
    float f0 = W[(size_t)h * KDIM + 2 * k2];
    float f1 = W[(size_t)h * KDIM + 2 * k2 + 1];
    bf16_t b0 = (bf16_t)f0, b1 = (bf16_t)f1;
    unsigned u = ((unsigned)__builtin_bit_cast(unsigned short, b1) << 16) |
                 (unsigned)__builtin_bit_cast(unsigned short, b0);
    ((unsigned*)Wb)[w] = u;
  }
}

__global__ __launch_bounds__(256, 1) void lstm_kernel(
    const float* __restrict__ X,
    const float* __restrict__ bf_, const float* __restrict__ bi_,
    const float* __restrict__ bg_, const float* __restrict__ bo_,
    const float* __restrict__ qs_, const float* __restrict__ qb_,
    float* __restrict__ out, unsigned* __restrict__ flags,
    const bf16_t* __restrict__ Wb, bf16_t* __restrict__ hbuf) {

  extern __shared__ char smem[];
  bf16_t* Wsl  = (bf16_t*)(smem);
  bf16_t* comb = (bf16_t*)(smem + 66048);
  float*  zbuf = (float*)(smem + 99072);   // [2][32][17]
  float*  cbuf = (float*)(smem + 103424);  // [16][8]
  float*  htmp = (float*)(smem + 103936);  // [16][8]
  float*  bbs  = (float*)(smem + 104448);  // [32]
  float*  qsh  = (float*)(smem + 104576);  // [8]
  float*  qbh  = (float*)(smem + 104608);  // [8]

#define WSL(s, k)  Wsl[(s) * LROW + (k)]
#define COMB(r, k) comb[(r) * LROW + (k)]
#define ZBUF(kh, sc, r) zbuf[((kh) * 32 + (sc)) * 17 + (r)]

  const int blk  = blockIdx.x;
  const int g    = blk >> 6;      // batch group 0..3
  const int j    = blk & 63;      // block in group -> h-col slice
  const int bo   = g * BB;        // batch offset
  const int hc0  = j * HCB;       // first owned h-col
  const int tid  = threadIdx.x;
  const int wave = tid >> 6;
  const int lane = tid & 63;

  // ---- one-time init ----
  {
    const uint4* src = (const uint4*)(Wb + (size_t)j * GC * KDIM);
#pragma unroll
    for (int ii = 0; ii < 16; ii++) {       // 4096 uint4 = 32x1024 bf16
      int idx = ii * 256 + tid;
      int s = idx >> 7, k8 = idx & 127;
      *(uint4*)&WSL(s, k8 * 8) = src[idx];
    }
    if (tid < 128) cbuf[tid] = 0.f;
    if (tid < HCB) { qsh[tid] = qs_[hc0 + tid]; qbh[tid] = qb_[hc0 + tid]; }
    if (tid < GC) {
      int q = tid >> 3, c = tid & 7;
      const float* bsrc = (q == 0) ? bf_ : (q == 1) ? bi_ : (q == 2) ? bg_ : bo_;
      bbs[tid] = bsrc[hc0 + c];
    }
  }
  __syncthreads();

  unsigned* hb32 = (unsigned*)hbuf;
  const unsigned* fl = flags + g * 64;

  for (int s = 0; s < T_STEPS; s++) {
    // ---- stage x_t (independent of sync) ----
    {
      const float4* xs = (const float4*)(X + ((size_t)s * BATCH + bo) * DIM);
#pragma unroll
      for (int ii = 0; ii < 8; ii++) {      // 16 rows x 128 float4
        int idx = ii * 256 + tid;
        int r = idx >> 7, q4 = idx & 127;
        float4 f = xs[r * 128 + q4];
        bf16x4 b;
        b[0] = (bf16_t)f.x; b[1] = (bf16_t)f.y; b[2] = (bf16_t)f.z; b[3] = (bf16_t)f.w;
        *(bf16x4*)&COMB(r, q4 * 4) = b;
      }
    }
    // ---- wait for h_{s-1} from group peers ----
    if (wave == 0) {
      int cap = 0;
      while (true) {
        unsigned v = __hip_atomic_load(&fl[lane], __ATOMIC_RELAXED, __HIP_MEMORY_SCOPE_AGENT);
        if (__all((int)(v >= (unsigned)s))) break;
        if (++cap > (1 << 18)) break;  // safety: wrong-answer beats hang
      }
    }
    __syncthreads();
    // ---- stage h_{s-1} (fresh addresses: normal cached loads are safe) ----
    {
      const uint4* hs = (const uint4*)(hbuf + ((size_t)s * BATCH + bo) * HID);
#pragma unroll
      for (int ii = 0; ii < 4; ii++) {      // 16 rows x 64 uint4
        int idx = ii * 256 + tid;
        int r = idx >> 6, q8 = idx & 63;
        *(uint4*)&COMB(r, 512 + q8 * 8) = hs[r * 64 + q8];
      }
    }
    __syncthreads();
    // ---- MFMA: wave (n = wave&1 -> 16 gate-cols, kh = wave>>1 -> K half) ----
    {
      const int n  = wave & 1;
      const int kh = wave >> 1;
      const int row = lane & 15;
      const int kq  = (lane >> 4) << 3;
      const bf16_t* arow = &COMB(row, kh * 512 + kq);
      const bf16_t* brow = &WSL(n * 16 + row, kh * 512 + kq);
      f32x4 acc = {0.f, 0.f, 0.f, 0.f};
#pragma unroll
      for (int kt = 0; kt < 16; kt++) {
        bf16x8 a = *(const bf16x8*)(arow + kt * 32);
        bf16x8 b = *(const bf16x8*)(brow + kt * 32);
        acc = __builtin_amdgcn_mfma_f32_16x16x32_bf16(a, b, acc, 0, 0, 0);
      }
      const int sc = n * 16 + (lane & 15);       // gate-col (C/D col = lane&15)
      const int rb = (lane >> 4) << 2;           // batch row base (C/D row)
#pragma unroll
      for (int q = 0; q < 4; q++) ZBUF(kh, sc, rb + q) = acc[q];
    }
    __syncthreads();
    // ---- epilogue: gates + cell update (fp32) ----
    if (tid < 128) {
      const int r = tid >> 3, c = tid & 7;
      float z0 = ZBUF(0, c, r)      + ZBUF(1, c, r)      + bbs[c];
      float z1 = ZBUF(0, 8 + c, r)  + ZBUF(1, 8 + c, r)  + bbs[8 + c];
      float z2 = ZBUF(0, 16 + c, r) + ZBUF(1, 16 + c, r) + bbs[16 + c];
      float z3 = ZBUF(0, 24 + c, r) + ZBUF(1, 24 + c, r) + bbs[24 + c];
      float qs = qsh[c], qb = qbh[c];
      float sf = 1.f / (1.f + expf(-z0));
      float si = 1.f / (1.f + expf(-z1));
      float sg = tanhf(z2);
      float so = 1.f / (1.f + expf(-z3));
      float fgate = tanhf(sf * qs + qb);
      float igate = tanhf(si * qs + qb);
      float ggate = tanhf(sg * qs + qb);
      float ogate = tanhf(so * qs + qb);
      float cn = fgate * cbuf[tid] + igate * ggate;
      cbuf[tid] = cn;
      float h = ogate * tanhf(cn);
      htmp[tid] = h;
      out[((size_t)s * BATCH + bo + r) * HID + hc0 + c] = h;
      if (s == T_STEPS - 1) {
        size_t base = (size_t)T_STEPS * BATCH * HID;
        out[base + (size_t)(bo + r) * HID + hc0 + c] = h;                  // hx
        out[base + (size_t)BATCH * HID + (size_t)(bo + r) * HID + hc0 + c] = cn;  // cx
      }
    }
    __syncthreads();
    // ---- publish h_s as bf16, write-through to coherent point ----
    if (tid < 64) {
      const int r = tid >> 2, cp = tid & 3;
      float f0 = htmp[r * HCB + cp * 2], f1 = htmp[r * HCB + cp * 2 + 1];
      bf16_t b0 = (bf16_t)f0, b1 = (bf16_t)f1;
      unsigned u = ((unsigned)__builtin_bit_cast(unsigned short, b1) << 16) |
                   (unsigned)__builtin_bit_cast(unsigned short, b0);
      size_t idx = (size_t)(s + 1) * (BATCH * HID / 2) + (size_t)(bo + r) * (HID / 2) +
                   (hc0 >> 1) + cp;
      __hip_atomic_store(&hb32[idx], u, __ATOMIC_RELAXED, __HIP_MEMORY_SCOPE_AGENT);
    }
    __syncthreads();  // drains all publish stores (vmcnt) before flag
    if (tid == 0) {
      __hip_atomic_store(&flags[blk], (unsigned)(s + 1), __ATOMIC_RELEASE,
                         __HIP_MEMORY_SCOPE_AGENT);
    }
  }
#undef WSL
#undef COMB
#undef ZBUF
}

extern "C" void kernel_launch(void* const* d_in, const int* in_sizes, int n_in,
                              void* d_out, int out_size, void* d_ws, size_t ws_size,
                              hipStream_t stream) {
  const float* X   = (const float*)d_in[0];
  const float* Wf  = (const float*)d_in[1];
  const float* bf  = (const float*)d_in[2];
  const float* Wi  = (const float*)d_in[3];
  const float* bi  = (const float*)d_in[4];
  const float* Wg  = (const float*)d_in[5];
  const float* bg  = (const float*)d_in[6];
  const float* Wo  = (const float*)d_in[7];
  const float* bo  = (const float*)d_in[8];
  const float* qs  = (const float*)d_in[9];
  const float* qb  = (const float*)d_in[10];
  float* out = (float*)d_out;

  if (ws_size < WS_REQUIRED) return;  // fail cleanly (absmax) rather than corrupt

  char* ws = (char*)d_ws;
  unsigned* flags = (unsigned*)(ws + WS_FLAGS_OFF);
  bf16_t* Wb   = (bf16_t*)(ws + WS_WB_OFF);
  bf16_t* hbuf = (bf16_t*)(ws + WS_HBUF_OFF);

  hipLaunchKernelGGL(prep_kernel, dim3(4096), dim3(256), 0, stream,
                     Wf, Wi, Wg, Wo, flags, Wb, hbuf);

  (void)hipFuncSetAttribute((const void*)lstm_kernel,
                            hipFuncAttributeMaxDynamicSharedMemorySize, SMEM_BYTES);

  void* args[] = {(void*)&X, (void*)&bf, (void*)&bi, (void*)&bg, (void*)&bo,
                  (void*)&qs, (void*)&qb, (void*)&out, (void*)&flags,
                  (void*)&Wb, (void*)&hbuf};
  hipLaunchCooperativeKernel((void*)lstm_kernel, dim3(NGROUPS * BPG), dim3(256),
                             args, SMEM_BYTES, stream);
}

// Round 2
// 5926.819 us; speedup vs baseline: 1.5662x; 1.5662x over previous
//
#include <hip/hip_runtime.h>

// R2: HybridQLSTM persistent-cooperative LSTM, latency-optimized rewrite.
// 256 blocks x 128 threads (2 waves). 4 batch-groups x 64 blocks.
// Per block: 8 h-cols => 32 gate-cols, gates interleaved [f,i,g,o] per h-col
// so each wave owns 16 gate-cols with FULL K=1024 -> no cross-wave exchange.
// x-fragments prefetched to registers (bf16, pre-converted in prep), h via LDS.
// 2 barriers/step; counted s_waitcnt vmcnt(16) keeps x-prefetch in flight
// across the pre-flag barrier; flag store relaxed (publish already drained).

#define T_STEPS 1024
#define BATCH   64
#define DIM     512
#define HID     512
#define NGROUPS 4
#define BPG     64
#define BB      16
#define NBLOCKS 256

typedef __bf16 bf16_t;
typedef __bf16 bf16x8 __attribute__((ext_vector_type(8)));
typedef float  f32x4  __attribute__((ext_vector_type(4)));

// ---- workspace layout ----
#define WS_FLAGS_OFF 0
#define WS_WB_OFF    4096
#define WB_BYTES     ((size_t)64*32*1024*2)            // 4 MB packed weights
#define WS_XB_OFF    (WS_WB_OFF + WB_BYTES)
#define XB_BYTES     ((size_t)T_STEPS*BATCH*DIM*2)     // 64 MB bf16 X
#define HBUF_BYTES   ((size_t)(T_STEPS+1)*BATCH*HID*2) // 67 MB h ring (t-indexed)
#define WS_FULL      (WS_XB_OFF + XB_BYTES + HBUF_BYTES)
#define WS_MIN       (WS_XB_OFF + HBUF_BYTES)          // fallback: no Xb

// ---- LDS layout ----
// Wsl  bf16 [32][1032]   @ 0      (66048 B)  rows = gate-cols (interleaved)
// hsh  bf16 [2][16][520] @ 66048  (33280 B)  double-buffered h tile
#define SMEM_BYTES 99328
#define LROW_W 1032   // 1024 + 8: rows shift 4 dwords -> b128 frag reads conflict-free
#define LROW_H 520    // 512 + 8

__device__ __forceinline__ unsigned pk2(float lo, float hi) {
  unsigned a = (unsigned)__builtin_bit_cast(unsigned short, (bf16_t)lo);
  unsigned b = (unsigned)__builtin_bit_cast(unsigned short, (bf16_t)hi);
  return (b << 16) | a;
}

__global__ void prep_kernel(const float* __restrict__ Wf, const float* __restrict__ Wi,
                            const float* __restrict__ Wg, const float* __restrict__ Wo,
                            const float* __restrict__ X,
                            unsigned* __restrict__ flags, unsigned* __restrict__ Wb,
                            unsigned* __restrict__ Xb, unsigned* __restrict__ hbuf0,
                            int hasXb) {
  size_t nthr = (size_t)gridDim.x * blockDim.x;
  size_t t0 = (size_t)blockIdx.x * blockDim.x + threadIdx.x;
  if (t0 < NBLOCKS) flags[t0] = 0u;
  for (size_t i = t0; i < (size_t)BATCH * HID / 2; i += nthr) hbuf0[i] = 0u;
  // weights: Wb[j][srow][k] bf16, srow = wv*16 + c, c = (hl<<2)|gate interleave
  for (size_t i = t0; i < (size_t)64 * 32 * 512; i += nthr) {
    int j = (int)(i >> 14);
    int rem = (int)(i & 16383);
    int srow = rem >> 9, k2 = rem & 511;
    int wv = srow >> 4, cc = srow & 15, gg = cc & 3, hl = cc >> 2;
    int h = j * 8 + wv * 4 + hl;
    const float* W = (gg == 0) ? Wf : (gg == 1) ? Wi : (gg == 2) ? Wg : Wo;
    float f0 = W[(size_t)h * 1024 + 2 * (size_t)k2];
    float f1 = W[(size_t)h * 1024 + 2 * (size_t)k2 + 1];
    Wb[i] = pk2(f0, f1);
  }
  if (hasXb) {
    for (size_t i = t0; i < (size_t)T_STEPS * BATCH * DIM / 2; i += nthr)
      Xb[i] = pk2(X[2 * i], X[2 * i + 1]);
  }
}

__global__ __launch_bounds__(128, 1) void lstm_kernel(
    const float* __restrict__ X, const bf16_t* __restrict__ Xb, int hasXb,
    const float* __restrict__ bf_, const float* __restrict__ bi_,
    const float* __restrict__ bg_, const float* __restrict__ bo_,
    const float* __restrict__ qs_, const float* __restrict__ qb_,
    float* __restrict__ out, unsigned* __restrict__ flags,
    const bf16_t* __restrict__ Wb, bf16_t* __restrict__ hbuf) {

  extern __shared__ char smem[];
  bf16_t* Wsl = (bf16_t*)smem;
  bf16_t* hsh = (bf16_t*)(smem + 66048);
#define WSL(r, k)    Wsl[(r) * LROW_W + (k)]
#define HSH(b, r, k) hsh[(b) * (16 * LROW_H) + (r) * LROW_H + (k)]

  const int blk = blockIdx.x;
  const int g = blk >> 6, j = blk & 63;
  const int bo2 = g * BB;
  const int tid = threadIdx.x, wv = tid >> 6, l = tid & 63;
  const int c = l & 15, rg = l >> 4, kq = rg * 8;   // frag col/rowgroup/k-chunk
  const int gate = c & 3, hl = c >> 2;
  const int hcol = j * 8 + wv * 4 + hl;
  const int brow = wv * 16 + c;                     // Wsl row for B-frag

  // ---- one-time: stage weight slice to LDS, load per-lane scalars ----
  {
    const uint4* src = (const uint4*)(Wb + (size_t)j * 32 * 1024);
#pragma unroll
    for (int ii = 0; ii < 32; ii++) {
      int idx = ii * 128 + tid;
      int sr = idx >> 7, k8 = idx & 127;
      *(uint4*)&WSL(sr, k8 * 8) = src[idx];
    }
  }
  const float* bsrc = (gate == 0) ? bf_ : (gate == 1) ? bi_ : (gate == 2) ? bg_ : bo_;
  const float bias = bsrc[hcol];
  const float qs = qs_[hcol], qb = qb_[hcol];
  float cst[4] = {0.f, 0.f, 0.f, 0.f};
  __syncthreads();

  unsigned* hb32 = (unsigned*)hbuf;
  const unsigned* fl = flags + g * 64;

  bf16x8 xf[16];
  auto load_x = [&](int sidx) {
    if (hasXb) {
      const bf16_t* xs = Xb + ((size_t)sidx * BATCH + bo2 + c) * DIM + kq;
#pragma unroll
      for (int kt = 0; kt < 16; kt++) xf[kt] = *(const bf16x8*)(xs + kt * 32);
    } else {
      const float* xs = X + ((size_t)sidx * BATCH + bo2 + c) * DIM + kq;
#pragma unroll
      for (int kt = 0; kt < 16; kt++) {
        const float4* p = (const float4*)(xs + kt * 32);
        float4 a = p[0], b = p[1];
        bf16x8 v;
        v[0] = (bf16_t)a.x; v[1] = (bf16_t)a.y; v[2] = (bf16_t)a.z; v[3] = (bf16_t)a.w;
        v[4] = (bf16_t)b.x; v[5] = (bf16_t)b.y; v[6] = (bf16_t)b.z; v[7] = (bf16_t)b.w;
        xf[kt] = v;
      }
    }
  };
  load_x(0);  // prologue prefetch

  for (int s = 0; s < T_STEPS; s++) {
    const int buf = s & 1;
    // ---- poll group flags (both waves independently; no barrier) ----
    {
      int cap = 0;
      while (true) {
        unsigned v = __hip_atomic_load(&fl[l], __ATOMIC_RELAXED, __HIP_MEMORY_SCOPE_AGENT);
        if (__all((int)(v >= (unsigned)s))) break;
        if (++cap > (1 << 20)) break;  // wrong-answer beats hang
      }
    }
    asm volatile("" ::: "memory");  // no load hoisting above the poll

    // ---- issue h_{s-1} loads (fresh t-indexed addresses; LLC-visible) ----
    uint4 hreg[8];
    {
      const uint4* hs = (const uint4*)(hbuf + ((size_t)s * BATCH + bo2) * HID);
#pragma unroll
      for (int ii = 0; ii < 8; ii++) hreg[ii] = hs[ii * 128 + tid];
    }
    // ---- x-half MFMAs (reg A-frags, hides h-load latency) ----
    f32x4 acc = {bias, bias, bias, bias};
#pragma unroll
    for (int kt = 0; kt < 16; kt++) {
      bf16x8 b = *(const bf16x8*)&WSL(brow, kq + kt * 32);
      acc = __builtin_amdgcn_mfma_f32_16x16x32_bf16(xf[kt], b, acc, 0, 0, 0);
    }
    // ---- stage h to LDS, barrier, h-half MFMAs ----
#pragma unroll
    for (int ii = 0; ii < 8; ii++) {
      int idx = ii * 128 + tid;
      int r = idx >> 6, ch = idx & 63;
      *(uint4*)&HSH(buf, r, ch * 8) = hreg[ii];
    }
    __syncthreads();
#pragma unroll
    for (int kt = 0; kt < 16; kt++) {
      bf16x8 a = *(const bf16x8*)&HSH(buf, c, kq + kt * 32);
      bf16x8 b = *(const bf16x8*)&WSL(brow, 512 + kq + kt * 32);
      acc = __builtin_amdgcn_mfma_f32_16x16x32_bf16(a, b, acc, 0, 0, 0);
    }
    // ---- epilogue: quad-lane gate exchange, fp32 cell update ----
    float hq[4];
#pragma unroll
    for (int q = 0; q < 4; q++) {
      float z = acc[q];
      float sg = 1.f / (1.f + __expf(-z));
      float th = 1.f - 2.f / (1.f + __expf(2.f * z));
      float a0 = (gate == 2) ? th : sg;
      float act = 1.f - 2.f / (1.f + __expf(2.f * (a0 * qs + qb)));  // tanh(a0*qs+qb)
      float x1 = __shfl_xor(act, 1), x2 = __shfl_xor(act, 2), x3 = __shfl_xor(act, 3);
      float vf = (gate == 0) ? act : (gate == 1) ? x1 : (gate == 2) ? x2 : x3;
      float vi = (gate == 0) ? x1 : (gate == 1) ? act : (gate == 2) ? x3 : x2;
      float vg = (gate == 0) ? x2 : (gate == 1) ? x3 : (gate == 2) ? act : x1;
      float vo = (gate == 0) ? x3 : (gate == 1) ? x2 : (gate == 2) ? x1 : act;
      float cn = vf * cst[q] + vi * vg;
      cst[q] = cn;
      hq[q] = vo * (1.f - 2.f / (1.f + __expf(2.f * cn)));
    }
    // ---- publish h_s (bf16 pairs, agent write-through) ----
    float hp0 = __shfl_xor(hq[0], 4), hp1 = __shfl_xor(hq[1], 4);
    float hp2 = __shfl_xor(hq[2], 4), hp3 = __shfl_xor(hq[3], 4);
    if ((c & 7) == 0) {
      int m = c >> 3;
      size_t bi2 = (size_t)(s + 1) * (BATCH * HID / 2) +
                   (size_t)(bo2 + rg * 4) * (HID / 2) + (size_t)(j * 4 + wv * 2 + m);
      __hip_atomic_store(&hb32[bi2 + 0],   pk2(hq[0], hp0), __ATOMIC_RELAXED, __HIP_MEMORY_SCOPE_AGENT);
      __hip_atomic_store(&hb32[bi2 + 256], pk2(hq[1], hp1), __ATOMIC_RELAXED, __HIP_MEMORY_SCOPE_AGENT);
      __hip_atomic_store(&hb32[bi2 + 512], pk2(hq[2], hp2), __ATOMIC_RELAXED, __HIP_MEMORY_SCOPE_AGENT);
      __hip_atomic_store(&hb32[bi2 + 768], pk2(hq[3], hp3), __ATOMIC_RELAXED, __HIP_MEMORY_SCOPE_AGENT);
    }
    // ---- out stores (off flag path; drained by counted vmcnt below) ----
    if (gate == 0) {
      size_t ob = ((size_t)s * BATCH + bo2 + rg * 4) * HID + hcol;
      out[ob] = hq[0]; out[ob + 512] = hq[1]; out[ob + 1024] = hq[2]; out[ob + 1536] = hq[3];
      if (s == T_STEPS - 1) {
        size_t hb = (size_t)T_STEPS * BATCH * HID + (size_t)(bo2 + rg * 4) * HID + hcol;
        size_t cb = hb + (size_t)BATCH * HID;
        out[hb] = hq[0]; out[hb + 512] = hq[1]; out[hb + 1024] = hq[2]; out[hb + 1536] = hq[3];
        out[cb] = cst[0]; out[cb + 512] = cst[1]; out[cb + 1024] = cst[2]; out[cb + 1536] = cst[3];
      }
    }
    // ---- prefetch x for s+1 (stays in flight across barrier+flag) ----
    asm volatile("" ::: "memory");  // keep stores (older) before prefetch loads
    load_x((s + 1 < T_STEPS) ? s + 1 : T_STEPS - 1);
    // drain publish+out (oldest) but NOT the 16 newest (x-prefetch loads)
    asm volatile("s_waitcnt vmcnt(16)" ::: "memory");
    __builtin_amdgcn_s_barrier();  // raw: no compiler vmcnt(0) drain
    if (tid == 0)
      __hip_atomic_store(&flags[blk], (unsigned)(s + 1), __ATOMIC_RELAXED,
                         __HIP_MEMORY_SCOPE_AGENT);
  }
#undef WSL
#undef HSH
}

extern "C" void kernel_launch(void* const* d_in, const int* in_sizes, int n_in,
                              void* d_out, int out_size, void* d_ws, size_t ws_size,
                              hipStream_t stream) {
  const float* X  = (const float*)d_in[0];
  const float* Wf = (const float*)d_in[1];
  const float* bf = (const float*)d_in[2];
  const float* Wi = (const float*)d_in[3];
  const float* bi = (const float*)d_in[4];
  const float* Wg = (const float*)d_in[5];
  const float* bg = (const float*)d_in[6];
  const float* Wo = (const float*)d_in[7];
  const float* bo = (const float*)d_in[8];
  const float* qs = (const float*)d_in[9];
  const float* qb = (const float*)d_in[10];
  float* out = (float*)d_out;

  if (ws_size < WS_MIN) return;  // can't run; fail loudly via absmax
  int hasXb = (ws_size >= WS_FULL) ? 1 : 0;

  char* ws = (char*)d_ws;
  unsigned* flags = (unsigned*)(ws + WS_FLAGS_OFF);
  bf16_t* Wb = (bf16_t*)(ws + WS_WB_OFF);
  bf16_t* Xb = (bf16_t*)(ws + WS_XB_OFF);
  bf16_t* hbuf = (bf16_t*)(ws + (hasXb ? (WS_XB_OFF + XB_BYTES) : WS_XB_OFF));

  hipLaunchKernelGGL(prep_kernel, dim3(4096), dim3(256), 0, stream,
                     Wf, Wi, Wg, Wo, X, flags, (unsigned*)Wb, (unsigned*)Xb,
                     (unsigned*)hbuf, hasXb);

  (void)hipFuncSetAttribute((const void*)lstm_kernel,
                            hipFuncAttributeMaxDynamicSharedMemorySize, SMEM_BYTES);

  const bf16_t* Xbc = Xb;
  const bf16_t* Wbc = Wb;
  void* args[] = {(void*)&X, (void*)&Xbc, (void*)&hasXb,
                  (void*)&bf, (void*)&bi, (void*)&bg, (void*)&bo,
                  (void*)&qs, (void*)&qb, (void*)&out, (void*)&flags,
                  (void*)&Wbc, (void*)&hbuf};
  hipLaunchCooperativeKernel((void*)lstm_kernel, dim3(NBLOCKS), dim3(128),
                             args, SMEM_BYTES, stream);
}